// Round 2
// baseline (2046.415 us; speedup 1.0000x reference)
//
#include <hip/hip_runtime.h>
#include <hip/hip_bf16.h>

// GPRPropagation: out = sum_k w_k * (D^-1/2 (A+I) D^-1/2)^k x, k=0..ORDER
// N=100000, F=128, E=1600000, ORDER=10.
// Strategy: build dst-sorted CSR once (count + scan + atomic place), then 10
// pull-style gather rounds (no atomics in the hot loop), fusing the weighted
// accumulation into d_out.
//
// NOTE: edge_index arrives as int32 (harness converts integer inputs to int).

#define F 128
#define SCAN_B 256

__global__ void count_kernel(const int* __restrict__ ei, int E,
                             int* __restrict__ cnt) {
    int e = blockIdx.x * blockDim.x + threadIdx.x;
    if (e < E) {
        int c = ei[(size_t)E + e];   // col = destination
        atomicAdd(&cnt[c], 1);
    }
}

__global__ void dinv_kernel(const int* __restrict__ cnt, float* __restrict__ dinv,
                            int N) {
    int i = blockIdx.x * blockDim.x + threadIdx.x;
    if (i < N) {
        // deg = in-edges + self loop (>=1 always)
        dinv[i] = rsqrtf((float)(cnt[i] + 1));
    }
}

// Block-local exclusive scan; offs[i] = exclusive prefix within block,
// bsums[b] = block total.
__global__ void scan1_kernel(const int* __restrict__ cnt, int* __restrict__ offs,
                             int* __restrict__ bsums, int N) {
    __shared__ int sm[SCAN_B];
    int i = blockIdx.x * SCAN_B + threadIdx.x;
    int v = (i < N) ? cnt[i] : 0;
    sm[threadIdx.x] = v;
    __syncthreads();
    for (int d = 1; d < SCAN_B; d <<= 1) {
        int t = (threadIdx.x >= d) ? sm[threadIdx.x - d] : 0;
        __syncthreads();
        sm[threadIdx.x] += t;
        __syncthreads();
    }
    if (i < N) offs[i] = sm[threadIdx.x] - v;
    if (threadIdx.x == SCAN_B - 1) bsums[blockIdx.x] = sm[SCAN_B - 1];
}

// Single-block chunked exclusive scan of block sums (in place).
__global__ void scan2_kernel(int* __restrict__ bsums, int nb) {
    __shared__ int sm[SCAN_B];
    __shared__ int carry;
    if (threadIdx.x == 0) carry = 0;
    __syncthreads();
    for (int base = 0; base < nb; base += SCAN_B) {
        int i = base + threadIdx.x;
        int v = (i < nb) ? bsums[i] : 0;
        sm[threadIdx.x] = v;
        __syncthreads();
        for (int d = 1; d < SCAN_B; d <<= 1) {
            int t = (threadIdx.x >= d) ? sm[threadIdx.x - d] : 0;
            __syncthreads();
            sm[threadIdx.x] += t;
            __syncthreads();
        }
        if (i < nb) bsums[i] = sm[threadIdx.x] - v + carry;
        __syncthreads();
        if (threadIdx.x == 0) carry += sm[SCAN_B - 1];
        __syncthreads();
    }
}

__global__ void scan3_kernel(int* __restrict__ offs, const int* __restrict__ bsums,
                             int* __restrict__ cursor, int N, int E) {
    int i = blockIdx.x * blockDim.x + threadIdx.x;
    if (i < N) {
        int o = offs[i] + bsums[i / SCAN_B];
        offs[i] = o;
        cursor[i] = o;
    }
    if (i == N) offs[N] = E;
}

// Scatter edges into CSR slots: record = (src int32, norm f32) packed in 8B.
__global__ void place_kernel(const int* __restrict__ ei, int E,
                             const float* __restrict__ dinv,
                             int* __restrict__ cursor, int2* __restrict__ edges) {
    int e = blockIdx.x * blockDim.x + threadIdx.x;
    if (e >= E) return;
    int r = ei[e];
    int c = ei[(size_t)E + e];
    int pos = atomicAdd(&cursor[c], 1);
    float w = dinv[r] * dinv[c];
    int2 p;
    p.x = r;
    p.y = __float_as_int(w);
    edges[pos] = p;
}

// One block per destination node, thread = feature column.
// acc = dinv[c]^2 * h_old[c,f] + sum_e w_e * h_old[src_e, f]
// h_new[c,f] = acc (skipped on last round); out accumulation fused.
__global__ __launch_bounds__(F) void prop_kernel(
    const float* __restrict__ h_old, float* __restrict__ h_new,
    float* __restrict__ out, const float* __restrict__ dinv,
    const int* __restrict__ offs, const int2* __restrict__ edges,
    const float* __restrict__ wts, int k, int first, int last) {
    const int c = blockIdx.x;
    const int f = threadIdx.x;
    const size_t ci = ((size_t)c << 7) + f;

    float hv = h_old[ci];
    float dc = dinv[c];
    float acc = dc * dc * hv;

    int beg = offs[c];
    int end = offs[c + 1];
    for (int e = beg; e < end; ++e) {
        int2 p = edges[e];
        acc = fmaf(__int_as_float(p.y), h_old[((size_t)p.x << 7) + f], acc);
    }

    if (!last) h_new[ci] = acc;
    if (first) {
        out[ci] = wts[0] * hv + wts[1] * acc;
    } else {
        out[ci] = fmaf(wts[k], acc, out[ci]);
    }
}

extern "C" void kernel_launch(void* const* d_in, const int* in_sizes, int n_in,
                              void* d_out, int out_size, void* d_ws, size_t ws_size,
                              hipStream_t stream) {
    const float* x = (const float*)d_in[0];
    const int* ei = (const int*)d_in[1];
    const float* wts = (const float*)d_in[2];
    float* out = (float*)d_out;

    const int NF = in_sizes[0];
    const int N = NF / F;              // 100000
    const int E = in_sizes[1] / 2;     // 1600000
    const int order = in_sizes[2] - 1; // 10

    // ---- carve workspace (256B aligned) ----
    char* p = (char*)d_ws;
    auto carve = [&](size_t bytes) {
        void* q = (void*)p;
        p += (bytes + 255) & ~(size_t)255;
        return q;
    };
    int nb = (N + SCAN_B - 1) / SCAN_B;
    int*   cnt    = (int*)carve(sizeof(int) * (size_t)N);  // reused as cursor
    int*   offs   = (int*)carve(sizeof(int) * (size_t)(N + 1));
    int*   bsums  = (int*)carve(sizeof(int) * (size_t)nb);
    float* dinv   = (float*)carve(sizeof(float) * (size_t)N);
    int2*  edges  = (int2*)carve(8ull * (size_t)E);
    float* hA     = (float*)carve(sizeof(float) * (size_t)NF);
    float* hB     = (float*)carve(sizeof(float) * (size_t)NF);
    int*   cursor = cnt;  // cnt is dead after scan1; scan3 rewrites it as cursor
    (void)ws_size;

    // ---- build normalization + CSR (per call; deterministic up to fp order) ----
    hipMemsetAsync(cnt, 0, sizeof(int) * (size_t)N, stream);
    count_kernel<<<(E + 255) / 256, 256, 0, stream>>>(ei, E, cnt);
    dinv_kernel<<<(N + 255) / 256, 256, 0, stream>>>(cnt, dinv, N);
    scan1_kernel<<<nb, SCAN_B, 0, stream>>>(cnt, offs, bsums, N);
    scan2_kernel<<<1, SCAN_B, 0, stream>>>(bsums, nb);
    scan3_kernel<<<(N + 1 + 255) / 256, 256, 0, stream>>>(offs, bsums, cursor, N, E);
    place_kernel<<<(E + 255) / 256, 256, 0, stream>>>(ei, E, dinv, cursor, edges);

    // ---- 10 propagation rounds, ping-pong h buffers, fused out accumulation ----
    const float* hin = x;
    float* hout = hA;
    for (int k = 1; k <= order; ++k) {
        int first = (k == 1);
        int last = (k == order);
        prop_kernel<<<N, F, 0, stream>>>(hin, hout, out, dinv, offs, edges, wts,
                                         k, first, last);
        hin = hout;
        hout = (hout == hA) ? hB : hA;
    }
}

// Round 3
// 1468.580 us; speedup vs baseline: 1.3935x; 1.3935x over previous
//
#include <hip/hip_runtime.h>
#include <hip/hip_bf16.h>

// GPRPropagation: out = sum_k w_k * (D^-1/2 (A+I) D^-1/2)^k x, k=0..ORDER
// N=100000, F=128, E=1600000, ORDER=10.
// dst-sorted CSR build once, then 10 pull-gather rounds (no atomics),
// PPR-weighted accumulation fused into the gather kernel.
// Round-2 lesson: compiler emits a fully serialized gather loop (VGPR=4,
// one outstanding 256B line/wave -> 2.7 TB/s). Manual unroll-4 for MLP.

#define F 128
#define SCAN_B 256

__global__ void count_kernel(const int* __restrict__ ei, int E,
                             int* __restrict__ cnt) {
    int e = blockIdx.x * blockDim.x + threadIdx.x;
    if (e < E) {
        int c = ei[(size_t)E + e];   // col = destination
        atomicAdd(&cnt[c], 1);
    }
}

__global__ void dinv_kernel(const int* __restrict__ cnt, float* __restrict__ dinv,
                            int N) {
    int i = blockIdx.x * blockDim.x + threadIdx.x;
    if (i < N) {
        dinv[i] = rsqrtf((float)(cnt[i] + 1));  // + self loop
    }
}

__global__ void scan1_kernel(const int* __restrict__ cnt, int* __restrict__ offs,
                             int* __restrict__ bsums, int N) {
    __shared__ int sm[SCAN_B];
    int i = blockIdx.x * SCAN_B + threadIdx.x;
    int v = (i < N) ? cnt[i] : 0;
    sm[threadIdx.x] = v;
    __syncthreads();
    for (int d = 1; d < SCAN_B; d <<= 1) {
        int t = (threadIdx.x >= d) ? sm[threadIdx.x - d] : 0;
        __syncthreads();
        sm[threadIdx.x] += t;
        __syncthreads();
    }
    if (i < N) offs[i] = sm[threadIdx.x] - v;
    if (threadIdx.x == SCAN_B - 1) bsums[blockIdx.x] = sm[SCAN_B - 1];
}

__global__ void scan2_kernel(int* __restrict__ bsums, int nb) {
    __shared__ int sm[SCAN_B];
    __shared__ int carry;
    if (threadIdx.x == 0) carry = 0;
    __syncthreads();
    for (int base = 0; base < nb; base += SCAN_B) {
        int i = base + threadIdx.x;
        int v = (i < nb) ? bsums[i] : 0;
        sm[threadIdx.x] = v;
        __syncthreads();
        for (int d = 1; d < SCAN_B; d <<= 1) {
            int t = (threadIdx.x >= d) ? sm[threadIdx.x - d] : 0;
            __syncthreads();
            sm[threadIdx.x] += t;
            __syncthreads();
        }
        if (i < nb) bsums[i] = sm[threadIdx.x] - v + carry;
        __syncthreads();
        if (threadIdx.x == 0) carry += sm[SCAN_B - 1];
        __syncthreads();
    }
}

__global__ void scan3_kernel(int* __restrict__ offs, const int* __restrict__ bsums,
                             int* __restrict__ cursor, int N, int E) {
    int i = blockIdx.x * blockDim.x + threadIdx.x;
    if (i < N) {
        int o = offs[i] + bsums[i / SCAN_B];
        offs[i] = o;
        cursor[i] = o;
    }
    if (i == N) offs[N] = E;
}

__global__ void place_kernel(const int* __restrict__ ei, int E,
                             const float* __restrict__ dinv,
                             int* __restrict__ cursor, int2* __restrict__ edges) {
    int e = blockIdx.x * blockDim.x + threadIdx.x;
    if (e >= E) return;
    int r = ei[e];
    int c = ei[(size_t)E + e];
    int pos = atomicAdd(&cursor[c], 1);
    float w = dinv[r] * dinv[c];
    int2 p;
    p.x = r;
    p.y = __float_as_int(w);
    edges[pos] = p;
}

// One block per destination node, thread = feature column.
// Manual unroll-4: 4 independent 256B/wave h-row gathers in flight.
__global__ __launch_bounds__(F) void prop_kernel(
    const float* __restrict__ h_old, float* __restrict__ h_new,
    float* __restrict__ out, const float* __restrict__ dinv,
    const int* __restrict__ offs, const int2* __restrict__ edges,
    const float* __restrict__ wts, int k, int first, int last) {
    const int c = blockIdx.x;
    const int f = threadIdx.x;
    const size_t ci = ((size_t)c << 7) + f;

    float hv = h_old[ci];
    float dc = dinv[c];
    float acc = dc * dc * hv;

    int e = offs[c];
    const int end = offs[c + 1];

    for (; e + 4 <= end; e += 4) {
        int2 p0 = edges[e + 0];
        int2 p1 = edges[e + 1];
        int2 p2 = edges[e + 2];
        int2 p3 = edges[e + 3];
        float g0 = h_old[((size_t)p0.x << 7) + f];
        float g1 = h_old[((size_t)p1.x << 7) + f];
        float g2 = h_old[((size_t)p2.x << 7) + f];
        float g3 = h_old[((size_t)p3.x << 7) + f];
        acc = fmaf(__int_as_float(p0.y), g0, acc);
        acc = fmaf(__int_as_float(p1.y), g1, acc);
        acc = fmaf(__int_as_float(p2.y), g2, acc);
        acc = fmaf(__int_as_float(p3.y), g3, acc);
    }
    for (; e < end; ++e) {
        int2 p = edges[e];
        acc = fmaf(__int_as_float(p.y), h_old[((size_t)p.x << 7) + f], acc);
    }

    if (!last) h_new[ci] = acc;
    if (first) {
        out[ci] = wts[0] * hv + wts[1] * acc;
    } else {
        out[ci] = fmaf(wts[k], acc, out[ci]);
    }
}

extern "C" void kernel_launch(void* const* d_in, const int* in_sizes, int n_in,
                              void* d_out, int out_size, void* d_ws, size_t ws_size,
                              hipStream_t stream) {
    const float* x = (const float*)d_in[0];
    const int* ei = (const int*)d_in[1];
    const float* wts = (const float*)d_in[2];
    float* out = (float*)d_out;

    const int NF = in_sizes[0];
    const int N = NF / F;              // 100000
    const int E = in_sizes[1] / 2;     // 1600000
    const int order = in_sizes[2] - 1; // 10

    char* p = (char*)d_ws;
    auto carve = [&](size_t bytes) {
        void* q = (void*)p;
        p += (bytes + 255) & ~(size_t)255;
        return q;
    };
    int nb = (N + SCAN_B - 1) / SCAN_B;
    int*   cnt    = (int*)carve(sizeof(int) * (size_t)N);  // reused as cursor
    int*   offs   = (int*)carve(sizeof(int) * (size_t)(N + 1));
    int*   bsums  = (int*)carve(sizeof(int) * (size_t)nb);
    float* dinv   = (float*)carve(sizeof(float) * (size_t)N);
    int2*  edges  = (int2*)carve(8ull * (size_t)E);
    float* hA     = (float*)carve(sizeof(float) * (size_t)NF);
    float* hB     = (float*)carve(sizeof(float) * (size_t)NF);
    int*   cursor = cnt;  // cnt dead after scan1
    (void)ws_size;

    hipMemsetAsync(cnt, 0, sizeof(int) * (size_t)N, stream);
    count_kernel<<<(E + 255) / 256, 256, 0, stream>>>(ei, E, cnt);
    dinv_kernel<<<(N + 255) / 256, 256, 0, stream>>>(cnt, dinv, N);
    scan1_kernel<<<nb, SCAN_B, 0, stream>>>(cnt, offs, bsums, N);
    scan2_kernel<<<1, SCAN_B, 0, stream>>>(bsums, nb);
    scan3_kernel<<<(N + 1 + 255) / 256, 256, 0, stream>>>(offs, bsums, cursor, N, E);
    place_kernel<<<(E + 255) / 256, 256, 0, stream>>>(ei, E, dinv, cursor, edges);

    const float* hin = x;
    float* hout = hA;
    for (int k = 1; k <= order; ++k) {
        int first = (k == 1);
        int last = (k == order);
        prop_kernel<<<N, F, 0, stream>>>(hin, hout, out, dinv, offs, edges, wts,
                                         k, first, last);
        hin = hout;
        hout = (hout == hA) ? hB : hA;
    }
}